// Round 1
// baseline (290.673 us; speedup 1.0000x reference)
//
#include <hip/hip_runtime.h>

#define NB 16
#define NH 128
#define NW 128
#define NC 64   // in channels
#define NO 64   // out channels
#define NM 16   // modes

// workspace float offsets (all multiples of 4 -> 16B aligned)
#define OFF_TW   0                          // 256 floats (float2[128] cos/sin)
#define OFF_WTR  1024                       // 1048576: Wt_re[kk][i][o]
#define OFF_WTI  (OFF_WTR + 1048576)        // 1048576: Wt_im
#define OFF_AR   (OFF_WTI + 1048576)        // 2097152: T1_re[b][ky][h][i], reused as T2_re[b][h][o][ky]
#define OFF_AI   (OFF_AR + 2097152)         // 2097152
#define OFF_XR   (OFF_AI + 2097152)         // 262144: X_re[kk][b][i]
#define OFF_XI   (OFF_XR + 262144)
#define OFF_OR   (OFF_XI + 262144)          // 262144: O_re[kk][b][o]
#define OFF_OI   (OFF_OR + 262144)

// ---------------------------------------------------------------- twiddle table
__global__ void k_tw(float* __restrict__ tw) {
    int t = threadIdx.x;  // 128 threads
    float ang = 6.2831853071795864769f * (float)t / 128.0f;
    tw[2 * t]     = cosf(ang);
    tw[2 * t + 1] = sinf(ang);
}

// ------------------------------------------------- weight transpose: (i,o,kx,ky) -> [kk][i][o]
__global__ __launch_bounds__(256) void k_wt(const float* __restrict__ wre,
                                            const float* __restrict__ wim,
                                            float* __restrict__ wtr,
                                            float* __restrict__ wti) {
    __shared__ float buf[64 * 257];  // [o][kk] padded, 64.25 KB
    const int i = blockIdx.x & 63;
    const float* src = (blockIdx.x < 64) ? wre : wim;
    float* dst       = (blockIdx.x < 64) ? wtr : wti;
    const float* s = src + (size_t)i * 16384;
    for (int t = threadIdx.x; t < 16384; t += 256) {
        int o = t >> 8, kk = t & 255;           // src linear = o*256 + kk
        buf[o * 257 + kk] = s[t];
    }
    __syncthreads();
    for (int t = threadIdx.x; t < 16384; t += 256) {
        int kk = t >> 6, o = t & 63;
        dst[(size_t)kk * 4096 + i * 64 + o] = buf[o * 257 + kk];  // coalesced 256B runs
    }
}

// ---------------------------------------------------------------- K1: w-DFT
// T1[b][ky][h][i] = sum_w x[b,h,w,i] * e^{-2pi i ky w/128}
__global__ __launch_bounds__(256) void k1_wdft(const float* __restrict__ x,
                                               const float* __restrict__ tw,
                                               float* __restrict__ t1r,
                                               float* __restrict__ t1i) {
    const int wid  = threadIdx.x >> 6;
    const int lane = threadIdx.x & 63;            // i
    const int slab = blockIdx.x * 4 + wid;        // b*128 + h
    const float* xp = x + (size_t)slab * (NW * NC) + lane;
    float ar[NM], ai[NM];
#pragma unroll
    for (int k = 0; k < NM; ++k) { ar[k] = 0.f; ai[k] = 0.f; }
    for (int w0 = 0; w0 < NW; w0 += 8) {
        float xv[8];
#pragma unroll
        for (int u = 0; u < 8; ++u) xv[u] = xp[(size_t)(w0 + u) * NC];
#pragma unroll
        for (int u = 0; u < 8; ++u) {
            const int w = w0 + u;
#pragma unroll
            for (int ky = 0; ky < NM; ++ky) {
                const int t = (ky * w) & 127;     // wave-uniform -> scalar loads
                const float c = tw[2 * t], sn = tw[2 * t + 1];
                ar[ky] = fmaf(xv[u], c, ar[ky]);
                ai[ky] = fmaf(xv[u], -sn, ai[ky]);
            }
        }
    }
    const int b = slab >> 7, h = slab & 127;
#pragma unroll
    for (int ky = 0; ky < NM; ++ky) {
        size_t idx = (((size_t)(b * NM + ky)) * NH + h) * NC + lane;
        t1r[idx] = ar[ky];
        t1i[idx] = ai[ky];
    }
}

// ---------------------------------------------------------------- K2a: h-DFT
// X[kk=(kx*16+ky)][b][i] = sum_h T1[b][ky][h][i] * e^{-2pi i kx h/128}
__global__ __launch_bounds__(256) void k2a_hdft(const float* __restrict__ t1r,
                                                const float* __restrict__ t1i,
                                                const float* __restrict__ tw,
                                                float* __restrict__ xre,
                                                float* __restrict__ xim) {
    __shared__ float lpr[4][NM][64];
    __shared__ float lpi[4][NM][64];
    const int bk   = blockIdx.x;                  // b*16 + ky
    const int hq   = threadIdx.x >> 6;
    const int lane = threadIdx.x & 63;            // i
    const float* pr = t1r + (size_t)bk * (NH * NC) + lane;
    const float* pi = t1i + (size_t)bk * (NH * NC) + lane;
    float xr[NM], xv[NM];
#pragma unroll
    for (int k = 0; k < NM; ++k) { xr[k] = 0.f; xv[k] = 0.f; }
    for (int hh = 0; hh < 32; ++hh) {
        const int h = hq * 32 + hh;
        const float re = pr[(size_t)h * NC];
        const float im = pi[(size_t)h * NC];
#pragma unroll
        for (int kx = 0; kx < NM; ++kx) {
            const int t = (kx * h) & 127;         // wave-uniform
            const float c = tw[2 * t], sn = tw[2 * t + 1];
            xr[kx] = fmaf(re, c, fmaf(im, sn, xr[kx]));   // (re+i im)(c - i s)
            xv[kx] = fmaf(im, c, fmaf(-re, sn, xv[kx]));
        }
    }
#pragma unroll
    for (int kx = 0; kx < NM; ++kx) {
        lpr[hq][kx][lane] = xr[kx];
        lpi[hq][kx][lane] = xv[kx];
    }
    __syncthreads();
    const int i  = threadIdx.x & 63;
    const int kq = threadIdx.x >> 6;
    const int b = bk >> 4, ky = bk & 15;
#pragma unroll
    for (int p = 0; p < 4; ++p) {
        const int kx = kq * 4 + p;
        float sr = lpr[0][kx][i] + lpr[1][kx][i] + lpr[2][kx][i] + lpr[3][kx][i];
        float si = lpi[0][kx][i] + lpi[1][kx][i] + lpi[2][kx][i] + lpi[3][kx][i];
        size_t idx = ((size_t)(kx * NM + ky)) * (NB * NC) + b * NC + i;
        xre[idx] = sr;
        xim[idx] = si;
    }
}

// ---------------------------------------------------------------- K2b: channel mix per mode
// O[kk][b][o] = sum_i X[kk][b][i] * W[kk][i][o]   (complex)
__global__ __launch_bounds__(256) void k2b_mix(const float* __restrict__ xre,
                                               const float* __restrict__ xim,
                                               const float* __restrict__ wtr,
                                               const float* __restrict__ wti,
                                               float* __restrict__ ore,
                                               float* __restrict__ oim) {
    __shared__ __align__(16) float lwr[4096], lwi[4096];  // [i][o]
    __shared__ __align__(16) float lxr[1024], lxi[1024];  // [b][i]
    const int kk = blockIdx.x;
    for (int t = threadIdx.x; t < 4096; t += 256) {
        lwr[t] = wtr[(size_t)kk * 4096 + t];
        lwi[t] = wti[(size_t)kk * 4096 + t];
    }
    for (int t = threadIdx.x; t < 1024; t += 256) {
        lxr[t] = xre[(size_t)kk * 1024 + t];
        lxi[t] = xim[(size_t)kk * 1024 + t];
    }
    __syncthreads();
    const int o  = threadIdx.x & 63;
    const int bq = threadIdx.x >> 6;
    float accr[4] = {0, 0, 0, 0}, acci[4] = {0, 0, 0, 0};
    for (int iq = 0; iq < 16; ++iq) {
        float xrv[4][4], xiv[4][4];               // [p][j]
#pragma unroll
        for (int p = 0; p < 4; ++p) {
            const int b = bq * 4 + p;
            float4 vr = ((const float4*)lxr)[b * 16 + iq];  // broadcast b128
            float4 vi = ((const float4*)lxi)[b * 16 + iq];
            xrv[p][0] = vr.x; xrv[p][1] = vr.y; xrv[p][2] = vr.z; xrv[p][3] = vr.w;
            xiv[p][0] = vi.x; xiv[p][1] = vi.y; xiv[p][2] = vi.z; xiv[p][3] = vi.w;
        }
#pragma unroll
        for (int j = 0; j < 4; ++j) {
            const int i2 = iq * 4 + j;
            const float wr = lwr[i2 * 64 + o];    // lane-consecutive, conflict-free
            const float wi = lwi[i2 * 64 + o];
#pragma unroll
            for (int p = 0; p < 4; ++p) {
                accr[p] = fmaf(xrv[p][j], wr, fmaf(-xiv[p][j], wi, accr[p]));
                acci[p] = fmaf(xrv[p][j], wi, fmaf(xiv[p][j], wr, acci[p]));
            }
        }
    }
#pragma unroll
    for (int p = 0; p < 4; ++p) {
        const int b = bq * 4 + p;
        ore[(size_t)kk * 1024 + b * 64 + o] = accr[p];
        oim[(size_t)kk * 1024 + b * 64 + o] = acci[p];
    }
}

// ---------------------------------------------------------------- K3: h-inverse
// T2[b][h][o][ky] = cfac(ky)/16384 * sum_kx O[kx*16+ky][b][o] * e^{+2pi i kx h/128}
__global__ __launch_bounds__(256) void k3_hidft(const float* __restrict__ ore,
                                                const float* __restrict__ oim,
                                                const float* __restrict__ tw,
                                                float* __restrict__ t2r,
                                                float* __restrict__ t2i) {
    __shared__ float ltc[128], lts[128];
    if (threadIdx.x < 128) {
        ltc[threadIdx.x] = tw[2 * threadIdx.x];
        lts[threadIdx.x] = tw[2 * threadIdx.x + 1];
    }
    __syncthreads();
    const int wid  = threadIdx.x >> 6;
    const int lane = threadIdx.x & 63;            // h within 64-half
    const int pair = blockIdx.x * 4 + wid;        // b*64 + o
    const int b = pair >> 6, o = pair & 63;
    float tr[2][NM], ti[2][NM];
#pragma unroll
    for (int hh = 0; hh < 2; ++hh)
#pragma unroll
        for (int k = 0; k < NM; ++k) { tr[hh][k] = 0.f; ti[hh][k] = 0.f; }
    for (int kx = 0; kx < NM; ++kx) {
        float orv[NM], oiv[NM];
#pragma unroll
        for (int ky = 0; ky < NM; ++ky) {         // uniform addresses -> scalar loads
            orv[ky] = ore[(size_t)(kx * NM + ky) * (NB * NO) + pair];
            oiv[ky] = oim[(size_t)(kx * NM + ky) * (NB * NO) + pair];
        }
#pragma unroll
        for (int hh = 0; hh < 2; ++hh) {
            const int h = hh * 64 + lane;
            const int t = (kx * h) & 127;         // lane-varying: LDS gather
            const float c = ltc[t], sn = lts[t];
#pragma unroll
            for (int ky = 0; ky < NM; ++ky) {
                tr[hh][ky] = fmaf(orv[ky], c, fmaf(-oiv[ky], sn, tr[hh][ky]));
                ti[hh][ky] = fmaf(orv[ky], sn, fmaf(oiv[ky], c, ti[hh][ky]));
            }
        }
    }
#pragma unroll
    for (int hh = 0; hh < 2; ++hh) {
        const int h = hh * 64 + lane;
        const size_t base = ((size_t)(b * NH + h) * NO + o) * NM;
#pragma unroll
        for (int ky = 0; ky < NM; ++ky) {
            const float sc = (ky == 0 ? 1.0f : 2.0f) * (1.0f / 16384.0f);
            t2r[base + ky] = tr[hh][ky] * sc;
            t2i[base + ky] = ti[hh][ky] * sc;
        }
    }
}

// ---------------------------------------------------------------- K5: w-inverse
// y[b,h,w,o] = sum_ky T2[b][h][o][ky] * e^{+2pi i ky w/128} (real part)
__global__ __launch_bounds__(256) void k5_widft(const float* __restrict__ t2r,
                                                const float* __restrict__ t2i,
                                                const float* __restrict__ tw,
                                                float* __restrict__ y) {
    const int wid  = threadIdx.x >> 6;
    const int lane = threadIdx.x & 63;            // o
    const int slab = blockIdx.x * 4 + wid;        // b*128 + h
    const float4* pr = (const float4*)(t2r + (size_t)slab * (NO * NM));
    const float4* pi = (const float4*)(t2i + (size_t)slab * (NO * NM));
    float trv[NM], tiv[NM];
#pragma unroll
    for (int q = 0; q < 4; ++q) {
        float4 vr = pr[lane * 4 + q];
        float4 vi = pi[lane * 4 + q];
        trv[4 * q] = vr.x; trv[4 * q + 1] = vr.y; trv[4 * q + 2] = vr.z; trv[4 * q + 3] = vr.w;
        tiv[4 * q] = vi.x; tiv[4 * q + 1] = vi.y; tiv[4 * q + 2] = vi.z; tiv[4 * q + 3] = vi.w;
    }
    float* yp = y + (size_t)slab * (NW * NC) + lane;
    for (int w = 0; w < NW; ++w) {
        float acc = 0.f;
#pragma unroll
        for (int ky = 0; ky < NM; ++ky) {
            const int t = (ky * w) & 127;         // wave-uniform -> scalar loads
            acc = fmaf(trv[ky], tw[2 * t], fmaf(-tiv[ky], tw[2 * t + 1], acc));
        }
        yp[(size_t)w * NC] = acc;
    }
}

extern "C" void kernel_launch(void* const* d_in, const int* in_sizes, int n_in,
                              void* d_out, int out_size, void* d_ws, size_t ws_size,
                              hipStream_t stream) {
    const float* x   = (const float*)d_in[0];
    const float* wre = (const float*)d_in[1];
    const float* wim = (const float*)d_in[2];
    float* ws  = (float*)d_ws;
    float* tw  = ws + OFF_TW;
    float* wtr = ws + OFF_WTR;
    float* wti = ws + OFF_WTI;
    float* ar  = ws + OFF_AR;   // T1 re, later T2 re
    float* ai  = ws + OFF_AI;   // T1 im, later T2 im
    float* xr  = ws + OFF_XR;
    float* xi  = ws + OFF_XI;
    float* orr = ws + OFF_OR;
    float* oii = ws + OFF_OI;
    float* y   = (float*)d_out;

    k_tw<<<1, 128, 0, stream>>>(tw);
    k_wt<<<128, 256, 0, stream>>>(wre, wim, wtr, wti);
    k1_wdft<<<512, 256, 0, stream>>>(x, tw, ar, ai);
    k2a_hdft<<<NB * NM, 256, 0, stream>>>(ar, ai, tw, xr, xi);
    k2b_mix<<<NM * NM, 256, 0, stream>>>(xr, xi, wtr, wti, orr, oii);
    k3_hidft<<<256, 256, 0, stream>>>(orr, oii, tw, ar, ai);   // ar/ai now hold T2
    k5_widft<<<512, 256, 0, stream>>>(ar, ai, tw, y);
}